// Round 4
// baseline (102.209 us; speedup 1.0000x reference)
//
#include <hip/hip_runtime.h>

#define S_COEF 0.025f
#define EPS_C  1e-6f
#define L2E    1.4426950408889634f   // log2(e)

typedef float f32x4 __attribute__((ext_vector_type(4)));

__device__ __forceinline__ float fexp2(float v) { return __builtin_amdgcn_exp2f(v); }
__device__ __forceinline__ float flog2(float v) { return __builtin_amdgcn_logf(v); }

// DPP-assisted add: v += dpp(v). old=0 so masked/out-of-bounds lanes add 0
// under either bound_ctrl interpretation.
template<int CTRL, int RM, bool BC>
__device__ __forceinline__ float dpp_add(float v) {
    int t = __builtin_amdgcn_update_dpp(0, __builtin_bit_cast(int, v),
                                        CTRL, RM, 0xF, BC);
    return v + __builtin_bit_cast(float, t);
}

// Canonical GCN wave64 inclusive prefix sum: 6 VALU ops, no LDS/DS.
__device__ __forceinline__ float wave_incl_scan(float v) {
    v = dpp_add<0x111, 0xF, true >(v);  // row_shr:1
    v = dpp_add<0x112, 0xF, true >(v);  // row_shr:2
    v = dpp_add<0x114, 0xF, true >(v);  // row_shr:4
    v = dpp_add<0x118, 0xF, true >(v);  // row_shr:8  -> per-16-row scans
    v = dpp_add<0x142, 0xA, false>(v);  // row_bcast:15 -> rows 1,3
    v = dpp_add<0x143, 0xC, false>(v);  // row_bcast:31 -> rows 2,3
    return v;
}

// One wave per (b,f) row; 8 consecutive t per lane per 512-wide group.
// EMA recurrence parallelized via rescaled DPP prefix-sum (u uniform):
//   m_in(lane) = u^(8*lane) * (carry + excl_prefix(b*u^(-8*lane)) * u^(-8))
// Pointwise pow math fused in base-2:
//   e*(EPS+M)^-alpha = exp2(x*log2e - alpha*log2(M+EPS)).
__global__ __launch_bounds__(256) void pcen_kernel(
    const float* __restrict__ x,
    const float* __restrict__ p_la,
    const float* __restrict__ p_ld,
    const float* __restrict__ p_lr,
    float* __restrict__ out,
    int rows, int T)
{
    const int lane = threadIdx.x & 63;
    const int wid  = blockIdx.x * (blockDim.x >> 6) + (threadIdx.x >> 6);
    if (wid >= rows) return;

    const float alpha = fminf(fmaxf(__expf(p_la[0]), 0.01f), 1.0f);
    const float delta = fminf(fmaxf(__expf(p_ld[0]), 0.01f), 5.0f);
    const float r     = fminf(fmaxf(__expf(p_lr[0]), 0.01f), 1.0f);
    const float dr    = fexp2(r * flog2(delta));     // delta^r

    const float u     = 1.0f - S_COEF;               // 0.975
    const float log2u = flog2(u);
    const float uinv8 = fexp2(-8.0f * log2u);                 // u^-8
    const float winv  = fexp2(-8.0f * (float)lane * log2u);   // u^(-8*lane)
    const float ul8   = fexp2( 8.0f * (float)lane * log2u);   // u^(+8*lane)

    const float* __restrict__ xr  = x   + (size_t)wid * T;
    float* __restrict__       orr = out + (size_t)wid * T;

    const int ngroups = (T + 511) >> 9;              // 16 for T=8000
    const int myoff   = lane * 8;
    float carry = 0.0f;

    f32x4 cur0 = {0.f,0.f,0.f,0.f}, cur1 = {0.f,0.f,0.f,0.f};
    if (myoff < T) {                                 // T%8==0 -> whole 8 valid
        cur0 = *(const f32x4*)(xr + myoff);
        cur1 = *(const f32x4*)(xr + myoff + 4);
    }

    for (int g = 0; g < ngroups; ++g) {
        const int base = g << 9;
        const int nidx = base + 512 + myoff;
        f32x4 nxt0 = {0.f,0.f,0.f,0.f}, nxt1 = {0.f,0.f,0.f,0.f};
        if (nidx < T) {
            nxt0 = *(const f32x4*)(xr + nidx);
            nxt1 = *(const f32x4*)(xr + nidx + 4);
        }

        float c[8] = {cur0.x, cur0.y, cur0.z, cur0.w,
                      cur1.x, cur1.y, cur1.z, cur1.w};
        float xl[8], se[8];
        #pragma unroll
        for (int i = 0; i < 8; ++i) {
            xl[i] = c[i] * L2E;
            se[i] = S_COEF * fexp2(xl[i]);
        }

        // local 8-step EMA with zero initial state
        float b = se[0];
        #pragma unroll
        for (int i = 1; i < 8; ++i) b = fmaf(u, b, se[i]);

        // rescaled inclusive prefix across lanes (DPP, no DS)
        const float scaled = b * winv;
        const float ps     = wave_incl_scan(scaled);
        const float excl   = ps - scaled;

        const float m_in = ul8 * fmaf(excl, uinv8, carry);

        float m[8];
        float mm = m_in;
        #pragma unroll
        for (int i = 0; i < 8; ++i) { mm = fmaf(u, mm, se[i]); m[i] = mm; }

        carry = __builtin_bit_cast(float,
                    __builtin_amdgcn_readlane(__builtin_bit_cast(int, m[7]), 63));

        float o[8];
        #pragma unroll
        for (int i = 0; i < 8; ++i) {
            const float ed = fexp2(fmaf(-alpha, flog2(m[i] + EPS_C), xl[i]));
            o[i] = fexp2(r * flog2(ed + delta)) - dr;
        }

        if (base + myoff < T) {
            f32x4 o0 = {o[0], o[1], o[2], o[3]};
            f32x4 o1 = {o[4], o[5], o[6], o[7]};
            __builtin_nontemporal_store(o0, (f32x4*)(orr + base + myoff));
            __builtin_nontemporal_store(o1, (f32x4*)(orr + base + myoff + 4));
        }
        cur0 = nxt0;
        cur1 = nxt1;
    }
}

extern "C" void kernel_launch(void* const* d_in, const int* in_sizes, int n_in,
                              void* d_out, int out_size, void* d_ws, size_t ws_size,
                              hipStream_t stream) {
    const float* x  = (const float*)d_in[0];
    const float* la = (const float*)d_in[1];
    const float* ld = (const float*)d_in[2];
    const float* lr = (const float*)d_in[3];
    float* out = (float*)d_out;

    const int T    = 8000;
    const int rows = in_sizes[0] / T;        // 64*128 = 8192
    const int wavesPerBlock = 4;             // blockDim 256
    const int blocks = (rows + wavesPerBlock - 1) / wavesPerBlock;

    hipLaunchKernelGGL(pcen_kernel, dim3(blocks), dim3(256), 0, stream,
                       x, la, ld, lr, out, rows, T);
}

// Round 5
// 85.021 us; speedup vs baseline: 1.2022x; 1.2022x over previous
//
#include <hip/hip_runtime.h>

#define S_COEF 0.025f
#define EPS_C  1e-6f
#define L2E    1.4426950408889634f   // log2(e)

typedef float f32x4 __attribute__((ext_vector_type(4)));

__device__ __forceinline__ float fexp2(float v) { return __builtin_amdgcn_exp2f(v); }
__device__ __forceinline__ float flog2(float v) { return __builtin_amdgcn_logf(v); }

// DPP-assisted add: v += dpp(v). old=0 so out-of-pattern lanes add 0.
template<int CTRL, int RM, bool BC>
__device__ __forceinline__ float dpp_add(float v) {
    int t = __builtin_amdgcn_update_dpp(0, __builtin_bit_cast(int, v),
                                        CTRL, RM, 0xF, BC);
    return v + __builtin_bit_cast(float, t);
}

// Canonical GCN wave64 inclusive prefix sum: 6 VALU ops, no DS (verified R4).
__device__ __forceinline__ float wave_incl_scan(float v) {
    v = dpp_add<0x111, 0xF, true >(v);  // row_shr:1
    v = dpp_add<0x112, 0xF, true >(v);  // row_shr:2
    v = dpp_add<0x114, 0xF, true >(v);  // row_shr:4
    v = dpp_add<0x118, 0xF, true >(v);  // row_shr:8  -> per-16-row scans
    v = dpp_add<0x142, 0xA, false>(v);  // row_bcast:15 -> rows 1,3
    v = dpp_add<0x143, 0xC, false>(v);  // row_bcast:31 -> rows 2,3
    return v;
}

// One wave per (b,f) row; 4 consecutive t per lane per 256-wide group
// (contiguous float4 store per lane -- keeps HBM writes fully coalesced;
// R4 showed 8/lane strided NT stores cause ~23% write amplification).
// EMA recurrence parallelized via rescaled DPP prefix-sum (u uniform).
// Pointwise pow math fused in base-2:
//   e*(EPS+M)^-alpha = exp2(x*log2e - alpha*log2(M+EPS)).
__global__ __launch_bounds__(256) void pcen_kernel(
    const float* __restrict__ x,
    const float* __restrict__ p_la,
    const float* __restrict__ p_ld,
    const float* __restrict__ p_lr,
    float* __restrict__ out,
    int rows, int T)
{
    const int lane = threadIdx.x & 63;
    const int wid  = blockIdx.x * (blockDim.x >> 6) + (threadIdx.x >> 6);
    if (wid >= rows) return;

    const float alpha = fminf(fmaxf(__expf(p_la[0]), 0.01f), 1.0f);
    const float delta = fminf(fmaxf(__expf(p_ld[0]), 0.01f), 5.0f);
    const float r     = fminf(fmaxf(__expf(p_lr[0]), 0.01f), 1.0f);
    const float dr    = fexp2(r * flog2(delta));     // delta^r

    const float u     = 1.0f - S_COEF;               // 0.975
    const float log2u = flog2(u);
    const float uinv4 = fexp2(-4.0f * log2u);                 // u^-4
    const float winv  = fexp2(-4.0f * (float)lane * log2u);   // u^(-4*lane)
    const float ul4   = fexp2( 4.0f * (float)lane * log2u);   // u^(+4*lane)

    const float* __restrict__ xr  = x   + (size_t)wid * T;
    float* __restrict__       orr = out + (size_t)wid * T;

    const int ngroups = (T + 255) >> 8;              // 32 for T=8000
    const int myoff   = lane * 4;
    float carry = 0.0f;

    f32x4 cur = (myoff < T) ? *(const f32x4*)(xr + myoff)
                            : (f32x4){0.f, 0.f, 0.f, 0.f};

    for (int g = 0; g < ngroups; ++g) {
        const int base = g << 8;
        const int nidx = base + 256 + myoff;
        f32x4 nxt = (nidx < T) ? *(const f32x4*)(xr + nidx)
                               : (f32x4){0.f, 0.f, 0.f, 0.f};

        // energies in base-2 domain; keep xl for the fused output pow
        const float xl0 = cur.x * L2E, xl1 = cur.y * L2E;
        const float xl2 = cur.z * L2E, xl3 = cur.w * L2E;

        const float se0 = S_COEF * fexp2(xl0);
        const float se1 = S_COEF * fexp2(xl1);
        const float se2 = S_COEF * fexp2(xl2);
        const float se3 = S_COEF * fexp2(xl3);

        // local 4-step EMA with zero initial state
        float b = se0;
        b = fmaf(u, b, se1);
        b = fmaf(u, b, se2);
        b = fmaf(u, b, se3);

        // rescaled inclusive prefix across lanes (DPP, no DS)
        const float scaled = b * winv;
        const float ps     = wave_incl_scan(scaled);
        const float excl   = ps - scaled;

        // incoming state: m_in = u^(4*lane) * (carry + excl * u^(-4))
        const float m_in = ul4 * fmaf(excl, uinv4, carry);

        const float m0 = fmaf(u, m_in, se0);
        const float m1 = fmaf(u, m0,   se1);
        const float m2 = fmaf(u, m1,   se2);
        const float m3 = fmaf(u, m2,   se3);

        carry = __builtin_bit_cast(float,
                    __builtin_amdgcn_readlane(__builtin_bit_cast(int, m3), 63));

        // ed = e*(EPS+m)^(-alpha) = exp2(xl - alpha*log2(m+EPS))
        const float ed0 = fexp2(fmaf(-alpha, flog2(m0 + EPS_C), xl0));
        const float ed1 = fexp2(fmaf(-alpha, flog2(m1 + EPS_C), xl1));
        const float ed2 = fexp2(fmaf(-alpha, flog2(m2 + EPS_C), xl2));
        const float ed3 = fexp2(fmaf(-alpha, flog2(m3 + EPS_C), xl3));

        // o = (ed + delta)^r - delta^r
        const float o0 = fexp2(r * flog2(ed0 + delta)) - dr;
        const float o1 = fexp2(r * flog2(ed1 + delta)) - dr;
        const float o2 = fexp2(r * flog2(ed2 + delta)) - dr;
        const float o3 = fexp2(r * flog2(ed3 + delta)) - dr;

        if (base + myoff < T) {
            f32x4 o4 = {o0, o1, o2, o3};
            __builtin_nontemporal_store(o4, (f32x4*)(orr + base + myoff));
        }
        cur = nxt;
    }
}

extern "C" void kernel_launch(void* const* d_in, const int* in_sizes, int n_in,
                              void* d_out, int out_size, void* d_ws, size_t ws_size,
                              hipStream_t stream) {
    const float* x  = (const float*)d_in[0];
    const float* la = (const float*)d_in[1];
    const float* ld = (const float*)d_in[2];
    const float* lr = (const float*)d_in[3];
    float* out = (float*)d_out;

    const int T    = 8000;
    const int rows = in_sizes[0] / T;        // 64*128 = 8192
    const int wavesPerBlock = 4;             // blockDim 256
    const int blocks = (rows + wavesPerBlock - 1) / wavesPerBlock;

    hipLaunchKernelGGL(pcen_kernel, dim3(blocks), dim3(256), 0, stream,
                       x, la, ld, lr, out, rows, T);
}

// Round 6
// 84.383 us; speedup vs baseline: 1.2113x; 1.0076x over previous
//
#include <hip/hip_runtime.h>

#define S_COEF 0.025f
#define EPS_C  1e-6f
#define L2E    1.4426950408889634f   // log2(e)

typedef float f32x4 __attribute__((ext_vector_type(4)));

__device__ __forceinline__ float fexp2(float v) { return __builtin_amdgcn_exp2f(v); }
__device__ __forceinline__ float flog2(float v) { return __builtin_amdgcn_logf(v); }

// DPP-assisted add: v += dpp(v). old=0 so out-of-pattern lanes add 0.
template<int CTRL, int RM, bool BC>
__device__ __forceinline__ float dpp_add(float v) {
    int t = __builtin_amdgcn_update_dpp(0, __builtin_bit_cast(int, v),
                                        CTRL, RM, 0xF, BC);
    return v + __builtin_bit_cast(float, t);
}

// Wave64 inclusive prefix sum: 6 VALU ops, no DS.
__device__ __forceinline__ float wave_incl_scan(float v) {
    v = dpp_add<0x111, 0xF, true >(v);  // row_shr:1
    v = dpp_add<0x112, 0xF, true >(v);  // row_shr:2
    v = dpp_add<0x114, 0xF, true >(v);  // row_shr:4
    v = dpp_add<0x118, 0xF, true >(v);  // row_shr:8
    v = dpp_add<0x142, 0xA, false>(v);  // row_bcast:15
    v = dpp_add<0x143, 0xC, false>(v);  // row_bcast:31
    return v;
}

// One wave per (b,f) row; 4 consecutive t per lane per 256-wide group.
// 2-deep global prefetch; 31 unguarded full groups + guarded tail.
// EMA via rescaled DPP prefix-sum; pow math fused in base-2.
struct PcenParams { float alpha, delta, r, dr, uinv4, winv, ul4; };

__device__ __forceinline__ void pcen_group(
    const f32x4 cur, float& carry, const PcenParams& P,
    float* __restrict__ dst, bool store_ok)
{
    const float u = 1.0f - S_COEF;

    const float xl0 = cur.x * L2E, xl1 = cur.y * L2E;
    const float xl2 = cur.z * L2E, xl3 = cur.w * L2E;

    const float se0 = S_COEF * fexp2(xl0);
    const float se1 = S_COEF * fexp2(xl1);
    const float se2 = S_COEF * fexp2(xl2);
    const float se3 = S_COEF * fexp2(xl3);

    float b = se0;
    b = fmaf(u, b, se1);
    b = fmaf(u, b, se2);
    b = fmaf(u, b, se3);

    const float scaled = b * P.winv;
    const float ps     = wave_incl_scan(scaled);
    const float excl   = ps - scaled;

    const float m_in = P.ul4 * fmaf(excl, P.uinv4, carry);

    const float m0 = fmaf(u, m_in, se0);
    const float m1 = fmaf(u, m0,   se1);
    const float m2 = fmaf(u, m1,   se2);
    const float m3 = fmaf(u, m2,   se3);

    carry = __builtin_bit_cast(float,
                __builtin_amdgcn_readlane(__builtin_bit_cast(int, m3), 63));

    const float ed0 = fexp2(fmaf(-P.alpha, flog2(m0 + EPS_C), xl0));
    const float ed1 = fexp2(fmaf(-P.alpha, flog2(m1 + EPS_C), xl1));
    const float ed2 = fexp2(fmaf(-P.alpha, flog2(m2 + EPS_C), xl2));
    const float ed3 = fexp2(fmaf(-P.alpha, flog2(m3 + EPS_C), xl3));

    const float o0 = fexp2(P.r * flog2(ed0 + P.delta)) - P.dr;
    const float o1 = fexp2(P.r * flog2(ed1 + P.delta)) - P.dr;
    const float o2 = fexp2(P.r * flog2(ed2 + P.delta)) - P.dr;
    const float o3 = fexp2(P.r * flog2(ed3 + P.delta)) - P.dr;

    if (store_ok) {
        f32x4 o4 = {o0, o1, o2, o3};
        __builtin_nontemporal_store(o4, (f32x4*)dst);
    }
}

__global__ __launch_bounds__(256) void pcen_kernel(
    const float* __restrict__ x,
    const float* __restrict__ p_la,
    const float* __restrict__ p_ld,
    const float* __restrict__ p_lr,
    float* __restrict__ out,
    int rows, int T)
{
    const int lane = threadIdx.x & 63;
    const int wid  = blockIdx.x * (blockDim.x >> 6) + (threadIdx.x >> 6);
    if (wid >= rows) return;

    PcenParams P;
    P.alpha = fminf(fmaxf(__expf(p_la[0]), 0.01f), 1.0f);
    P.delta = fminf(fmaxf(__expf(p_ld[0]), 0.01f), 5.0f);
    P.r     = fminf(fmaxf(__expf(p_lr[0]), 0.01f), 1.0f);
    P.dr    = fexp2(P.r * flog2(P.delta));

    const float u     = 1.0f - S_COEF;
    const float log2u = flog2(u);
    P.uinv4 = fexp2(-4.0f * log2u);
    P.winv  = fexp2(-4.0f * (float)lane * log2u);
    P.ul4   = fexp2( 4.0f * (float)lane * log2u);

    const float* __restrict__ xr  = x   + (size_t)wid * T;
    float* __restrict__       orr = out + (size_t)wid * T;

    const int nfull = T >> 8;                // 31 full groups (T=8000)
    const int myoff = lane * 4;
    float carry = 0.0f;

    // prefetch depth 2 (T >= 512 for full groups >= 2)
    f32x4 cur = *(const f32x4*)(xr + myoff);
    f32x4 n1  = *(const f32x4*)(xr + 256 + myoff);

    for (int g = 0; g < nfull; ++g) {
        const int pidx = ((g + 2) << 8) + myoff;
        f32x4 n2 = (pidx < T) ? *(const f32x4*)(xr + pidx)
                              : (f32x4){0.f, 0.f, 0.f, 0.f};

        pcen_group(cur, carry, P, orr + (g << 8) + myoff, true);

        cur = n1;
        n1  = n2;
    }

    // tail group: t in [nfull*256, T); valid lanes only
    const int tbase = nfull << 8;
    if (tbase < T)
        pcen_group(cur, carry, P, orr + tbase + myoff, tbase + myoff < T);
}

extern "C" void kernel_launch(void* const* d_in, const int* in_sizes, int n_in,
                              void* d_out, int out_size, void* d_ws, size_t ws_size,
                              hipStream_t stream) {
    const float* x  = (const float*)d_in[0];
    const float* la = (const float*)d_in[1];
    const float* ld = (const float*)d_in[2];
    const float* lr = (const float*)d_in[3];
    float* out = (float*)d_out;

    const int T    = 8000;
    const int rows = in_sizes[0] / T;        // 64*128 = 8192
    const int wavesPerBlock = 4;             // blockDim 256
    const int blocks = (rows + wavesPerBlock - 1) / wavesPerBlock;

    hipLaunchKernelGGL(pcen_kernel, dim3(blocks), dim3(256), 0, stream,
                       x, la, ld, lr, out, rows, T);
}